// Round 16
// baseline (61.641 us; speedup 1.0000x reference)
//
#include <hip/hip_runtime.h>
#include <math.h>

// ConcentrationPredictor: 32 RK4 steps of dc/dt = flux(c), per-cell MLP D_eff.
// R16: wave-autonomous rk4 (NO barriers in the step loop) + asinh-space
// cubic-Hermite ret table in LDS. R6's validated interleaved 2-cells/thread
// shfl exchange (distance-1 up/down, even/odd BC split) with the MLP replaced
// by the table gather. The R4-R9 barrier-free spills were LICM hoisting 527
// loop-invariant weight loads; the table gather is data-dependent -> nothing
// to hoist -> no spill. 4 waves/block share one staged table; waves free-run.
// Geometry: wave window 128, halo 32 (S_FUSE=8), inner 64; 1024 waves =
// 256 blocks x 4 dispatches; redundancy 2x (same as R14).

constexpr int TPB     = 256;               // 4 autonomous waves per block
constexpr int S_FUSE  = 8;                 // RK4 steps per dispatch
constexpr int W_HALO  = 4 * S_FUSE;        // 32 cells/side per wave
constexpr int W_INNER = 64;                // valid cells per wave (window 128)

constexpr int   NTAB   = 5633;             // nodes: u in [-22,22], h = 1/128
constexpr float VSLOPE = 88.72283911167299f;  // ln2 * 128
constexpr float VOFF   = 2816.0f;             // -U_MIN * 128
constexpr float HSTEP  = 0.0078125f;          // h = 1/128

// float-layout of d_ws / LDS:
//   [0 .. 2*NTAB)        float2 table (v, dv/du) per node
//   [2*NTAB]             scale = 10^p_exp
//   [2*NTAB+1 .. +32]    A[s] = (t[s+1]-t[s]) * 0.3125f
constexpr int F_SCALE = 2 * NTAB;          // 11266
constexpr int F_A0    = 2 * NTAB + 1;      // 11267
constexpr int F_TOT   = 2 * NTAB + 1 + 32; // 11299
constexpr int F4_TOT  = (F_TOT + 3) / 4;   // 2825 float4s staged

// ---------- prep: build ret table (value + d/du) with accurate math ----------
__global__ __launch_bounds__(256)
void build_tab_kernel(const float* __restrict__ W1, const float* __restrict__ b1,
                      const float* __restrict__ W2, const float* __restrict__ b2,
                      const float* __restrict__ W3, const float* __restrict__ b3,
                      const float* __restrict__ W4, const float* __restrict__ b4,
                      const float* __restrict__ p_exp, const float* __restrict__ t,
                      int nsteps, float* __restrict__ wsf)
{
    const int i = blockIdx.x * blockDim.x + threadIdx.x;
    if (i > NTAB) {
        const int s = i - NTAB - 1;          // aux: A[s]
        if (s < nsteps && s < 32)
            wsf[F_A0 + s] = (t[s + 1] - t[s]) * 0.3125f;
        return;
    }
    if (i == NTAB) {                          // aux: scale
        wsf[F_SCALE] = powf(10.0f, p_exp[0]);
        return;
    }
    const float u  = -22.0f + (float)i * HSTEP;
    const float y  = sinhf(u);     // MLP input at this node
    const float yd = coshf(u);     // dy/du

    float h[15], hd[15], g[15], gd[15];
#pragma unroll
    for (int j = 0; j < 15; ++j) {
        float a  = fmaf(y, W1[j], b1[j]);
        float ad = yd * W1[j];
        float th = tanhf(a);
        h[j]  = th;
        hd[j] = (1.0f - th * th) * ad;
    }
#pragma unroll
    for (int j = 0; j < 15; ++j) {
        float a = b2[j], ad = 0.0f;
#pragma unroll
        for (int k = 0; k < 15; ++k) {
            a  = fmaf(h[k],  W2[k * 15 + j], a);
            ad = fmaf(hd[k], W2[k * 15 + j], ad);
        }
        float th = tanhf(a);
        g[j]  = th;
        gd[j] = (1.0f - th * th) * ad;
    }
#pragma unroll
    for (int j = 0; j < 15; ++j) {
        float a = b3[j], ad = 0.0f;
#pragma unroll
        for (int k = 0; k < 15; ++k) {
            a  = fmaf(g[k],  W3[k * 15 + j], a);
            ad = fmaf(gd[k], W3[k * 15 + j], ad);
        }
        float th = tanhf(a);
        h[j]  = th;
        hd[j] = (1.0f - th * th) * ad;
    }
    float o = b4[0], od = 0.0f;
#pragma unroll
    for (int k = 0; k < 15; ++k) {
        o  = fmaf(h[k],  W4[k], o);
        od = fmaf(hd[k], W4[k], od);
    }
    const float s = 1.0f / (1.0f + expf(-o));     // sigmoid
    wsf[2 * i]     = s;                           // value
    wsf[2 * i + 1] = s * (1.0f - s) * od;         // d/du
}

// ---------- table evaluation: ret(c*scale) via asinh + cubic Hermite ----------
__device__ __forceinline__ float ret_tab(float c, float scale,
                                         const float2* __restrict__ tab)
{
    const float y  = c * scale;
    const float ay = fabsf(y);
    // u = asinh(y); v = (u + 22)*128 folded into one fma off v_log_f32 (log2):
    // v = sign(y)*log2(|y|+sqrt(y^2+1))*(ln2*128) + 2816
    const float w  = ay + __builtin_amdgcn_sqrtf(fmaf(ay, ay, 1.0f));
    const float m  = copysignf(VSLOPE, y);
    float v = fmaf(__builtin_amdgcn_logf(w), m, VOFF);
    v = fminf(fmaxf(v, 0.0f), (float)(NTAB - 2) + 0.999f);  // clamp to table
    const int   i   = (int)v;
    const float tau = v - (float)i;

    const float2 A = tab[i];
    const float2 B = tab[i + 1];
    const float t2 = tau * tau;
    const float t3 = t2 * tau;
    // cubic Hermite with segment length HSTEP
    return A.x * (2.0f * t3 - 3.0f * t2 + 1.0f)
         + B.x * (3.0f * t2 - 2.0f * t3)
         + HSTEP * (A.y * (t3 - 2.0f * t2 + tau) + B.y * (t3 - t2));
}

__global__ __launch_bounds__(TPB)
void rk4_kernel(const float* __restrict__ src,   // state at step s0 [N]
                float* __restrict__ out,         // [T, N]
                const float* __restrict__ wsf,   // table+aux in d_ws
                int N, int s0, int nsub)
{
    __shared__ float tlds[F4_TOT * 4];   // table + aux (float4-staged)

    const int tid = threadIdx.x;

    // stage table+aux, float4-vectorized (shared by the block's 4 waves)
    {
        const float4* __restrict__ s4 = (const float4*)wsf;
        float4* d4 = (float4*)tlds;
        for (int i = tid; i < F4_TOT; i += TPB) d4[i] = s4[i];
    }

    const int lane = tid & 63;
    const int wave = tid >> 6;
    const int base = (blockIdx.x * (TPB / 64) + wave) * W_INNER - W_HALO;
    const int g0   = base + 2 * lane;    // even cell
    const int g1   = g0 + 1;             // odd cell

    float cx = src[min(max(g0, 0), N - 1)];
    float cy = src[min(max(g1, 0), N - 1)];

    // valid window cells [W_HALO, W_HALO + W_INNER) = lanes [16, 48)
    const bool valid = (lane >= W_HALO / 2) && (lane < (W_HALO + W_INNER) / 2);

    if (s0 == 0 && valid) {
        if ((unsigned)g0 < (unsigned)N) out[g0] = cx;
        if ((unsigned)g1 < (unsigned)N) out[g1] = cy;
    }

    __syncthreads();                  // table staged (only barrier)
    const float2* __restrict__ tab = (const float2*)tlds;
    const float scale = tlds[F_SCALE];

    // one flux stage, k~ = flux/D0 (D0 folded into A).
    // Interleaved neighbors (validated R6): even cell 2L: cl = shfl_up(cy),
    // cr = own cy; odd cell 2L+1: cl = own cx, cr = shfl_down(cx).
    // Lane-edge self-clamp garbage lands in halo lanes only.
    auto stage = [&](float ccx, float ccy, float& fx, float& fy) {
        float up = __shfl_up(ccy, 1, 64);     // cell 2L-1
        float dn = __shfl_down(ccx, 1, 64);   // cell 2L+2
        float rx = ret_tab(ccx, scale, tab);
        float ry = ret_tab(ccy, scale, tab);
        if (g0 == 0)                    // N even -> only even comp can be cell 0
            fx = rx * ((1.0f - ccx) + (ccy - ccx));
        else
            fx = rx * (up + ccy - 2.0f * ccx);
        if (g1 == N - 1)                // N-1 odd -> only odd comp
            fy = ry * ((ccx - ccy) + (0.0125f * (ccx - ccy) - ccy));
        else
            fy = ry * (ccx + dn - 2.0f * ccy);
    };

#pragma unroll 1
    for (int s = 0; s < nsub; ++s) {
        const float A = tlds[F_A0 + s0 + s];   // uniform broadcast, dt*D0

        float k1x, k1y, k2x, k2y, k3x, k3y, k4x, k4y;
        stage(cx, cy, k1x, k1y);
        float c2x = fmaf(0.5f * A, k1x, cx), c2y = fmaf(0.5f * A, k1y, cy);
        stage(c2x, c2y, k2x, k2y);
        float c3x = fmaf(0.5f * A, k2x, cx), c3y = fmaf(0.5f * A, k2y, cy);
        stage(c3x, c3y, k3x, k3y);
        float c4x = fmaf(A, k3x, cx), c4y = fmaf(A, k3y, cy);
        stage(c4x, c4y, k4x, k4y);

        cx = fmaf(A * (1.0f / 6.0f), k1x + 2.0f * (k2x + k3x) + k4x, cx);
        cy = fmaf(A * (1.0f / 6.0f), k1y + 2.0f * (k2y + k3y) + k4y, cy);

        if (valid) {
            float* row = out + (size_t)(s0 + s + 1) * N;
            if ((unsigned)g0 < (unsigned)N) row[g0] = cx;
            if ((unsigned)g1 < (unsigned)N) row[g1] = cy;
        }
    }
}

extern "C" void kernel_launch(void* const* d_in, const int* in_sizes, int n_in,
                              void* d_out, int out_size, void* d_ws, size_t ws_size,
                              hipStream_t stream)
{
    const float* c0    = (const float*)d_in[0];
    const float* t     = (const float*)d_in[1];
    const float* W1    = (const float*)d_in[2];
    const float* b1    = (const float*)d_in[3];
    const float* W2    = (const float*)d_in[4];
    const float* b2    = (const float*)d_in[5];
    const float* W3    = (const float*)d_in[6];
    const float* b3    = (const float*)d_in[7];
    const float* W4    = (const float*)d_in[8];
    const float* b4    = (const float*)d_in[9];
    const float* p_exp = (const float*)d_in[10];

    float* out = (float*)d_out;
    float* wsf = (float*)d_ws;   // F_TOT floats = 45196 B

    const int N      = in_sizes[0];       // 65536
    const int nsteps = in_sizes[1] - 1;   // 32

    // build ret table + aux (scale, A[s])
    const int tgrid = (NTAB + 1 + 32 + 255) / 256;
    hipLaunchKernelGGL(build_tab_kernel, dim3(tgrid), dim3(256), 0, stream,
                       W1, b1, W2, b2, W3, b3, W4, b4, p_exp, t, nsteps, wsf);

    // 1024 wave-windows per dispatch -> 256 blocks of 4 waves
    const int nwaves = (N + W_INNER - 1) / W_INNER;            // 1024
    const int grid   = (nwaves + (TPB / 64) - 1) / (TPB / 64); // 256

    for (int s0 = 0; s0 < nsteps; s0 += S_FUSE) {   // 4 dispatches
        const int nsub = min(S_FUSE, nsteps - s0);
        const float* src = (s0 == 0) ? c0 : out + (size_t)s0 * N;
        hipLaunchKernelGGL(rk4_kernel, dim3(grid), dim3(TPB), 0, stream,
                           src, out, wsf, N, s0, nsub);
    }
}